// Round 6
// baseline (3170.033 us; speedup 1.0000x reference)
//
#include <hip/hip_runtime.h>

#define NTIPS 512
#define DIM   510          // internal nodes = ntips - 2
#define TOTAL 1022
#define BS    64
#define ITERS 50

typedef unsigned short u16;
typedef unsigned int   u32;

// bf16 helpers (RNE, matching XLA/ml_dtypes casts)
__device__ __forceinline__ u16 f2bf(float x) {
    u32 u = __float_as_uint(x);
    return (u16)((u + 0x7FFFu + ((u >> 16) & 1u)) >> 16);
}
__device__ __forceinline__ float bf2f(u16 h) {
    return __uint_as_float(((u32)h) << 16);
}

// ---------------------------------------------------------------------------
// State: X iterates stored as bf16.
//   A (X_even, incl. X0) : d_ws, BS*DIM*512 u16  (33.4 MB)
//   B (X_odd)            : upper half of d_out's 134 MB ((u16*)d_out + 33,488,896)
//   part[b][0..511]      : f32 per-(tree,row) L1 deltas, after A in ws
//   go[1..50] + parity[51]: ints after part
// Final convert writes all of d_out as fp32 (identity + f32(bf16 X)).
// ---------------------------------------------------------------------------

// init: A = bf16(1/512) = 0x3B00 everywhere; part = 0; go = 0.
__global__ __launch_bounds__(256) void init_kernel(u16* __restrict__ A,
                                                   float* __restrict__ part,
                                                   int* __restrict__ go) {
    size_t g = (size_t)blockIdx.x * 256 + threadIdx.x;   // uint4 index over A
    uint4 fill;
    fill.x = fill.y = fill.z = fill.w = 0x3B003B00u;     // 4x (2 bf16 of 1/512)
    reinterpret_cast<uint4*>(A)[g] = fill;               // 8 u16 per thread
    if (g < (size_t)BS * 512 / 4)
        reinterpret_cast<float4*>(part)[g] = make_float4(0.f, 0.f, 0.f, 0.f);
    if (g < 52) go[g] = 0;
}

// step s (gated on go[s-1] for s>=2): dst[b,i,:] = bf16(f32sum(3 neighbors)/3);
// part[b][i] = f32 sum over features of |bf16(new - old)|.
__global__ __launch_bounds__(128) void step_kernel(
        const int* __restrict__ edge,
        const u16* __restrict__ src, u16* __restrict__ dst,
        float* __restrict__ part, const int* __restrict__ go, int s) {
    if (s > 1 && go[s - 1] == 0) return;        // block-uniform gate

    const int tid = threadIdx.x;                // 0..127 -> features 4t..4t+3
    const int i = blockIdx.x;                   // internal node 0..509
    const int b = blockIdx.y;                   // tree 0..63

    const int* e = edge + ((size_t)b * TOTAL + NTIPS + i) * 3;
    const int e0 = e[0], e1 = e[1], e2 = e[2];

    const u16* srcb = src + (size_t)b * DIM * NTIPS;
    const int f0 = tid << 2;

    float acc[4] = {0.f, 0.f, 0.f, 0.f};
    #pragma unroll
    for (int k = 0; k < 3; ++k) {
        const int ek = (k == 0) ? e0 : (k == 1) ? e1 : e2;
        if (ek < NTIPS) {
            if ((ek >> 2) == tid) acc[ek & 3] += 1.0f;   // identity one-hot (bf16 1.0 exact)
        } else {
            const ushort4 r = *reinterpret_cast<const ushort4*>(
                srcb + (size_t)(ek - NTIPS) * NTIPS + f0);
            acc[0] += bf2f(r.x); acc[1] += bf2f(r.y);
            acc[2] += bf2f(r.z); acc[3] += bf2f(r.w);
        }
    }

    // mean in f32, cast to bf16 (jnp: f32-accumulated reduce, result cast back)
    u16 nb[4]; float nf_[4];
    #pragma unroll
    for (int c = 0; c < 4; ++c) {
        nb[c] = f2bf(acc[c] / 3.0f);
        nf_[c] = bf2f(nb[c]);
    }
    ushort4 st; st.x = nb[0]; st.y = nb[1]; st.z = nb[2]; st.w = nb[3];
    *reinterpret_cast<ushort4*>(dst + (size_t)b * DIM * NTIPS +
                                (size_t)i * NTIPS + f0) = st;

    // elementwise delta: bf16(new - old), |.|, f32-accumulate
    const ushort4 ov = *reinterpret_cast<const ushort4*>(
        srcb + (size_t)i * NTIPS + f0);
    float d = 0.f;
    d += fabsf(bf2f(f2bf(nf_[0] - bf2f(ov.x))));
    d += fabsf(bf2f(f2bf(nf_[1] - bf2f(ov.y))));
    d += fabsf(bf2f(f2bf(nf_[2] - bf2f(ov.z))));
    d += fabsf(bf2f(f2bf(nf_[3] - bf2f(ov.w))));

    __shared__ float red[128];                  // pure-LDS block reduce
    red[tid] = d;
    __syncthreads();
    #pragma unroll
    for (int w = 64; w > 0; w >>= 1) {
        if (tid < w) red[tid] += red[tid + w];
        __syncthreads();
    }
    if (tid == 0) part[(size_t)b * 512 + i] = red[0];
}

// reduce after step s: per tree, f32-sum part[b][0..511]; lnorm = bf16(sum/261120);
// go[s] = any tree with lnorm > bf16(1e-5)  (jnp weak-type: scalar cast to bf16).
__global__ __launch_bounds__(256) void reduce_kernel(
        const float* __restrict__ part, int* __restrict__ go, int s) {
    __shared__ float red[256];
    __shared__ int s_any;
    const int tid = threadIdx.x;
    if (tid == 0) s_any = 0;
    __syncthreads();
    const float tol_bf = bf2f(f2bf(1e-5f));     // bf16(1e-5) ~= 1.0014e-5
    for (int b = 0; b < BS; ++b) {
        red[tid] = part[(size_t)b * 512 + tid] + part[(size_t)b * 512 + 256 + tid];
        __syncthreads();
        #pragma unroll
        for (int w = 128; w > 0; w >>= 1) {
            if (tid < w) red[tid] += red[tid + w];
            __syncthreads();
        }
        if (tid == 0) {
            const float lnorm = bf2f(f2bf(red[0] / 261120.0f));
            if (lnorm > tol_bf) s_any = 1;
        }
        __syncthreads();
    }
    if (tid == 0) go[s] = s_any;
}

// parity of last executed step (s ran iff s==1 or go[s-1] != 0)
__global__ void preselect_kernel(int* __restrict__ go) {
    int s0 = 1;
    for (int s = 2; s <= ITERS; ++s) {
        if (!go[s - 1]) break;
        s0 = s;
    }
    go[51] = (s0 & 1);
}

// if final X is odd-parity (in B), copy B -> A. grid (DIM, BS) x 128.
__global__ __launch_bounds__(128) void fixX_kernel(
        const u16* __restrict__ B, u16* __restrict__ A,
        const int* __restrict__ go) {
    if (go[51] == 0) return;
    const size_t off = ((size_t)blockIdx.y * DIM + blockIdx.x) * NTIPS
                       + (threadIdx.x << 2);
    *reinterpret_cast<ushort4*>(A + off) =
        *reinterpret_cast<const ushort4*>(B + off);
}

// write d_out as fp32: rows 0..511 identity, rows 512..1021 = f32(bf16 A).
// grid (TOTAL, BS) x 64; each thread handles 8 features.
__global__ __launch_bounds__(64) void convert_kernel(
        const u16* __restrict__ A, float* __restrict__ out) {
    const int r = blockIdx.x;                   // 0..1021
    const int b = blockIdx.y;
    const int f0 = threadIdx.x << 3;            // 8 floats per thread
    float4 lo, hi;
    if (r < NTIPS) {
        lo.x = (r == f0 + 0) ? 1.0f : 0.0f;
        lo.y = (r == f0 + 1) ? 1.0f : 0.0f;
        lo.z = (r == f0 + 2) ? 1.0f : 0.0f;
        lo.w = (r == f0 + 3) ? 1.0f : 0.0f;
        hi.x = (r == f0 + 4) ? 1.0f : 0.0f;
        hi.y = (r == f0 + 5) ? 1.0f : 0.0f;
        hi.z = (r == f0 + 6) ? 1.0f : 0.0f;
        hi.w = (r == f0 + 7) ? 1.0f : 0.0f;
    } else {
        const u16* row = A + (((size_t)b * DIM + (r - NTIPS)) * NTIPS + f0);
        const ushort4 a = *reinterpret_cast<const ushort4*>(row);
        const ushort4 c = *reinterpret_cast<const ushort4*>(row + 4);
        lo.x = bf2f(a.x); lo.y = bf2f(a.y); lo.z = bf2f(a.z); lo.w = bf2f(a.w);
        hi.x = bf2f(c.x); hi.y = bf2f(c.y); hi.z = bf2f(c.z); hi.w = bf2f(c.w);
    }
    float* dst = out + ((size_t)b * TOTAL + r) * NTIPS + f0;
    *reinterpret_cast<float4*>(dst)     = lo;
    *reinterpret_cast<float4*>(dst + 4) = hi;
}

extern "C" void kernel_launch(void* const* d_in, const int* in_sizes, int n_in,
                              void* d_out, int out_size, void* d_ws, size_t ws_size,
                              hipStream_t stream) {
    const int* edge = (const int*)d_in[1];       // (BS, TOTAL, 3) int32

    u16*   A    = (u16*)d_ws;                    // bf16 X_even, BS*DIM*512
    float* part = (float*)(A + (size_t)BS * DIM * NTIPS);
    int*   go   = (int*)(part + (size_t)BS * 512);

    // B = bf16 X_odd, placed in the upper half of d_out's 134 MB fp32 buffer
    u16* B = (u16*)d_out + (size_t)BS * TOTAL * NTIPS;   // byte offset 66,977,792
    float* out = (float*)d_out;

    const unsigned ablocks = (unsigned)((size_t)BS * DIM * NTIPS / 8 / 256); // 8160
    init_kernel<<<ablocks, 256, 0, stream>>>(A, part, go);

    dim3 grid(DIM, BS);
    for (int s = 1; s <= ITERS; ++s) {
        if (s & 1)
            step_kernel<<<grid, 128, 0, stream>>>(edge, A, B, part, go, s);
        else
            step_kernel<<<grid, 128, 0, stream>>>(edge, B, A, part, go, s);
        reduce_kernel<<<1, 256, 0, stream>>>(part, go, s);
    }

    preselect_kernel<<<1, 1, 0, stream>>>(go);
    fixX_kernel<<<grid, 128, 0, stream>>>(B, A, go);
    convert_kernel<<<dim3(TOTAL, BS), 64, 0, stream>>>(A, out);
}

// Round 7
// 1613.239 us; speedup vs baseline: 1.9650x; 1.9650x over previous
//
#include <hip/hip_runtime.h>
#include <hip/hip_cooperative_groups.h>

namespace cg = cooperative_groups;

#define NTIPS 512
#define DIM   510          // internal nodes = ntips - 2
#define TOTAL 1022
#define BS    64
#define ITERS 50
#define NBLK  512          // cooperative grid: 2 blocks/CU on 256 CUs
#define NTHR  256          // 4 waves/block -> 2048 waves total
#define NWAVE (NBLK * 4)   // one row-group per wave
#define NROWS (BS * DIM)   // 32640

typedef unsigned short u16;
typedef unsigned int   u32;

// bf16 helpers (RNE, matching XLA/ml_dtypes casts) — identical to R6
__device__ __forceinline__ u16 f2bf(float x) {
    u32 u = __float_as_uint(x);
    return (u16)((u + 0x7FFFu + ((u >> 16) & 1u)) >> 16);
}
__device__ __forceinline__ float bf2f(u16 h) {
    return __uint_as_float(((u32)h) << 16);
}

// ---------------------------------------------------------------------------
// Single persistent cooperative kernel.
// State: A (bf16 X_even) in ws; B (bf16 X_odd) in upper half of d_out;
// part[t] per-row f32 L1 deltas in ws; go[1..50] flags in ws.
// Phases: init -> sync -> { step s: phase1 rows -> sync -> phase2 reduce ->
// sync -> break if converged } -> (copy B->A if odd, sync) -> fp32 convert.
// All arithmetic bit-identical to the validated R6 step.
// ---------------------------------------------------------------------------
__global__ __launch_bounds__(NTHR, 2) void persist_kernel(
        const int* __restrict__ edge, u16* __restrict__ A, u16* B,
        float* __restrict__ part, int* __restrict__ go, float* out) {
    cg::grid_group gg = cg::this_grid();
    const int tid  = threadIdx.x;
    const int gidx = blockIdx.x * NTHR + tid;
    const int wv   = gidx >> 6;          // global wave id 0..NWAVE-1
    const int lane = tid & 63;

    __shared__ float r2[NTHR];

    // ---- init: A := bf16(1/512) everywhere; go := 0 ----
    {
        uint4 fill; fill.x = fill.y = fill.z = fill.w = 0x3B003B00u;
        uint4* A4 = reinterpret_cast<uint4*>(A);
        const size_t n4 = (size_t)NROWS * NTIPS / 8;   // 2,088,960
        for (size_t q = gidx; q < n4; q += (size_t)NBLK * NTHR) A4[q] = fill;
        if (gidx <= ITERS) go[gidx] = 0;
    }
    gg.sync();

    const float tol_bf = bf2f(f2bf(1e-5f));

    int s;
    for (s = 1; s <= ITERS; ++s) {
        const u16* src = (s & 1) ? A : B;
        u16*       dst = (s & 1) ? B : A;

        // ---- phase 1: one wave per row; lane owns features 8*lane..8*lane+7
        const int f0 = lane << 3;
        for (int t = wv; t < NROWS; t += NWAVE) {
            const int b = t / DIM;           // wave-uniform
            const int i = t - b * DIM;
            const int* e = edge + ((size_t)b * TOTAL + NTIPS + i) * 3;
            const int e0 = e[0], e1 = e[1], e2 = e[2];
            const u16* srcb = src + (size_t)b * DIM * NTIPS;

            float acc[8] = {0.f,0.f,0.f,0.f,0.f,0.f,0.f,0.f};
            #pragma unroll
            for (int k = 0; k < 3; ++k) {
                const int ek = (k == 0) ? e0 : (k == 1) ? e1 : e2;
                if (ek < NTIPS) {            // wave-uniform branch
                    #pragma unroll
                    for (int j = 0; j < 8; ++j)
                        acc[j] += (ek == f0 + j) ? 1.0f : 0.0f;
                } else {
                    const u16* row = srcb + (size_t)(ek - NTIPS) * NTIPS + f0;
                    const ushort4 a = *reinterpret_cast<const ushort4*>(row);
                    const ushort4 c = *reinterpret_cast<const ushort4*>(row + 4);
                    acc[0] += bf2f(a.x); acc[1] += bf2f(a.y);
                    acc[2] += bf2f(a.z); acc[3] += bf2f(a.w);
                    acc[4] += bf2f(c.x); acc[5] += bf2f(c.y);
                    acc[6] += bf2f(c.z); acc[7] += bf2f(c.w);
                }
            }

            u16 nb[8]; float nf_[8];
            #pragma unroll
            for (int j = 0; j < 8; ++j) {    // mean in f32, RNE cast to bf16
                nb[j] = f2bf(acc[j] / 3.0f);
                nf_[j] = bf2f(nb[j]);
            }
            u16* drow = dst + (size_t)b * DIM * NTIPS + (size_t)i * NTIPS + f0;
            ushort4 s0v; s0v.x = nb[0]; s0v.y = nb[1]; s0v.z = nb[2]; s0v.w = nb[3];
            ushort4 s1v; s1v.x = nb[4]; s1v.y = nb[5]; s1v.z = nb[6]; s1v.w = nb[7];
            *reinterpret_cast<ushort4*>(drow)     = s0v;
            *reinterpret_cast<ushort4*>(drow + 4) = s1v;

            // delta vs old row: bf16(new - old), |.|, f32 accumulate
            const u16* orow = srcb + (size_t)i * NTIPS + f0;
            const ushort4 o0 = *reinterpret_cast<const ushort4*>(orow);
            const ushort4 o1 = *reinterpret_cast<const ushort4*>(orow + 4);
            float d = 0.f;
            d += fabsf(bf2f(f2bf(nf_[0] - bf2f(o0.x))));
            d += fabsf(bf2f(f2bf(nf_[1] - bf2f(o0.y))));
            d += fabsf(bf2f(f2bf(nf_[2] - bf2f(o0.z))));
            d += fabsf(bf2f(f2bf(nf_[3] - bf2f(o0.w))));
            d += fabsf(bf2f(f2bf(nf_[4] - bf2f(o1.x))));
            d += fabsf(bf2f(f2bf(nf_[5] - bf2f(o1.y))));
            d += fabsf(bf2f(f2bf(nf_[6] - bf2f(o1.z))));
            d += fabsf(bf2f(f2bf(nf_[7] - bf2f(o1.w))));
            #pragma unroll
            for (int off = 32; off > 0; off >>= 1) d += __shfl_down(d, off);
            if (lane == 0) part[t] = d;      // deterministic per-row value
        }
        gg.sync();

        // ---- phase 2: blocks 0..63 reduce one tree each (fixed order) ----
        if (blockIdx.x < BS) {
            const int b = blockIdx.x;
            const float* p = part + (size_t)b * DIM;
            float v = p[tid];
            if (tid + 256 < DIM) v += p[tid + 256];
            r2[tid] = v;
            __syncthreads();
            #pragma unroll
            for (int w = 128; w > 0; w >>= 1) {
                if (tid < w) r2[tid] += r2[tid + w];
                __syncthreads();
            }
            if (tid == 0) {
                const float lnorm = bf2f(f2bf(r2[0] / 261120.0f));
                if (lnorm > tol_bf) atomicOr(&go[s], 1);
            }
        }
        gg.sync();

        if (__hip_atomic_load(&go[s], __ATOMIC_RELAXED,
                              __HIP_MEMORY_SCOPE_AGENT) == 0)
            break;                           // uniform across the grid
    }

    const int fs = (s <= ITERS) ? s : ITERS; // last executed step
    if (fs & 1) {                            // final X in B -> copy to A
        uint4* A4 = reinterpret_cast<uint4*>(A);
        const uint4* B4 = reinterpret_cast<const uint4*>(B);
        const size_t n4 = (size_t)NROWS * NTIPS / 8;
        for (size_t q = gidx; q < n4; q += (size_t)NBLK * NTHR) A4[q] = B4[q];
        gg.sync();
    }

    // ---- convert: d_out fp32 = [identity ; f32(bf16 A)] ----
    for (int R = wv; R < BS * TOTAL; R += NWAVE) {
        const int b = R / TOTAL;             // wave-uniform
        const int r = R - b * TOTAL;
        const int f0 = lane << 3;
        float4 lo, hi;
        if (r < NTIPS) {
            lo.x = (r == f0 + 0) ? 1.0f : 0.0f;
            lo.y = (r == f0 + 1) ? 1.0f : 0.0f;
            lo.z = (r == f0 + 2) ? 1.0f : 0.0f;
            lo.w = (r == f0 + 3) ? 1.0f : 0.0f;
            hi.x = (r == f0 + 4) ? 1.0f : 0.0f;
            hi.y = (r == f0 + 5) ? 1.0f : 0.0f;
            hi.z = (r == f0 + 6) ? 1.0f : 0.0f;
            hi.w = (r == f0 + 7) ? 1.0f : 0.0f;
        } else {
            const u16* arow = A + ((size_t)b * DIM + (r - NTIPS)) * NTIPS + f0;
            const ushort4 a = *reinterpret_cast<const ushort4*>(arow);
            const ushort4 c = *reinterpret_cast<const ushort4*>(arow + 4);
            lo.x = bf2f(a.x); lo.y = bf2f(a.y); lo.z = bf2f(a.z); lo.w = bf2f(a.w);
            hi.x = bf2f(c.x); hi.y = bf2f(c.y); hi.z = bf2f(c.z); hi.w = bf2f(c.w);
        }
        float* drow = out + (size_t)R * NTIPS + f0;
        *reinterpret_cast<float4*>(drow)     = lo;
        *reinterpret_cast<float4*>(drow + 4) = hi;
    }
}

extern "C" void kernel_launch(void* const* d_in, const int* in_sizes, int n_in,
                              void* d_out, int out_size, void* d_ws, size_t ws_size,
                              hipStream_t stream) {
    const int* edge = (const int*)d_in[1];       // (BS, TOTAL, 3) int32

    u16*   A    = (u16*)d_ws;                    // bf16 X_even, NROWS*512 u16
    float* part = (float*)(A + (size_t)NROWS * NTIPS);   // NROWS f32
    int*   go   = (int*)(part + NROWS);                  // go[0..50]

    u16*   B   = (u16*)d_out + (size_t)BS * TOTAL * NTIPS; // upper half of d_out
    float* out = (float*)d_out;

    void* args[] = { (void*)&edge, (void*)&A, (void*)&B,
                     (void*)&part, (void*)&go, (void*)&out };
    hipLaunchCooperativeKernel((const void*)persist_kernel,
                               dim3(NBLK), dim3(NTHR), args, 0, stream);
}